// Round 2
// baseline (892.303 us; speedup 1.0000x reference)
//
#include <hip/hip_runtime.h>
#include <stdint.h>

#define N_NODES 50000
#define N_EDGES 800000
#define IN_DIM 512
#define OUT_DIM 512
#define KDIM 1024   // [agg | x]
#define NDIM 1024   // [loc | scale-pre]

typedef __bf16 bf16x8 __attribute__((ext_vector_type(8)));
typedef float f32x4 __attribute__((ext_vector_type(4)));

__device__ __forceinline__ unsigned short f2bf(float f) {
    union { float f; unsigned u; } c; c.f = f;
    unsigned u = c.u;
    u += 0x7fffu + ((u >> 16) & 1u);   // round-to-nearest-even
    return (unsigned short)(u >> 16);
}
__device__ __forceinline__ float bf2f(unsigned short h) {
    union { unsigned u; float f; } c; c.u = ((unsigned)h) << 16;
    return c.f;
}

// ---------------- Phase 1: x -> bf16 ----------------
__global__ void xconv_kernel(const float* __restrict__ x, unsigned short* __restrict__ xb) {
    int i = blockIdx.x * blockDim.x + threadIdx.x;   // unit = 4 floats
    const int n4 = N_NODES * IN_DIM / 4;
    if (i < n4) {
        float4 v = ((const float4*)x)[i];
        ushort4 o;
        o.x = f2bf(v.x); o.y = f2bf(v.y); o.z = f2bf(v.z); o.w = f2bf(v.w);
        ((ushort4*)xb)[i] = o;
    }
}

// ---------------- Phase 2: CSR build ----------------
// NOTE: harness delivers integer inputs as int32 (per contract), NOT int64.
__global__ void count_kernel(const int* __restrict__ ei, int* __restrict__ counts) {
    int i = blockIdx.x * blockDim.x + threadIdx.x;
    if (i < N_EDGES) {
        int dst = ei[N_EDGES + i];
        dst = min(max(dst, 0), N_NODES - 1);   // defensive clamp: fault -> wrong answer
        atomicAdd(&counts[dst], 1);
    }
}

// single-block exclusive scan over N_NODES counts -> offs[N_NODES+1], cursor copy
__global__ void scan_kernel(const int* __restrict__ cnt, int* __restrict__ offs,
                            int* __restrict__ cursor, int n) {
    __shared__ int warp_sums[16];
    __shared__ int s_base;
    int tid = threadIdx.x;
    int lane = tid & 63;
    int w = tid >> 6;
    if (tid == 0) s_base = 0;
    __syncthreads();
    for (int start = 0; start < n; start += 1024) {
        int i = start + tid;
        int v = (i < n) ? cnt[i] : 0;
        int s = v;  // inclusive wave scan
        #pragma unroll
        for (int d = 1; d < 64; d <<= 1) {
            int t = __shfl_up(s, d, 64);
            if (lane >= d) s += t;
        }
        if (lane == 63) warp_sums[w] = s;
        __syncthreads();
        if (w == 0) {
            int ws = (lane < 16) ? warp_sums[lane] : 0;
            #pragma unroll
            for (int d = 1; d < 16; d <<= 1) {
                int t = __shfl_up(ws, d, 64);
                if (lane >= d) ws += t;
            }
            if (lane < 16) warp_sums[lane] = ws;  // inclusive wave totals
        }
        __syncthreads();
        int base = s_base + (w > 0 ? warp_sums[w - 1] : 0);
        int excl = base + s - v;
        if (i < n) { offs[i] = excl; cursor[i] = excl; }
        if (i == n - 1) offs[n] = excl + v;
        __syncthreads();
        if (tid == 0) s_base += warp_sums[15];
        __syncthreads();
    }
}

__global__ void fill_kernel(const int* __restrict__ ei, int* __restrict__ cursor,
                            int* __restrict__ bucket) {
    int i = blockIdx.x * blockDim.x + threadIdx.x;
    if (i < N_EDGES) {
        int src = ei[i];
        int dst = ei[N_EDGES + i];
        src = min(max(src, 0), N_NODES - 1);
        dst = min(max(dst, 0), N_NODES - 1);
        int pos = atomicAdd(&cursor[dst], 1);
        bucket[pos] = src;
    }
}

// ---------------- Phase 3: per-node aggregation (fp32 acc, bf16 out) ----------------
__global__ __launch_bounds__(256) void aggregate_kernel(
    const unsigned short* __restrict__ xb, const int* __restrict__ offs,
    const int* __restrict__ bucket, unsigned short* __restrict__ aggb) {
    int n = blockIdx.x;
    int t = threadIdx.x;   // handles bf16 pair -> dims 2t, 2t+1
    int beg = offs[n], end = offs[n + 1];
    const unsigned* xw = (const unsigned*)xb;
    float ax = 0.f, ay = 0.f;
    for (int e = beg; e < end; ++e) {
        int s = bucket[e];
        unsigned v = xw[(size_t)s * (IN_DIM / 2) + t];
        ax += bf2f((unsigned short)(v & 0xffffu));
        ay += bf2f((unsigned short)(v >> 16));
    }
    unsigned o = (unsigned)f2bf(ax) | ((unsigned)f2bf(ay) << 16);
    ((unsigned*)aggb)[(size_t)n * (IN_DIM / 2) + t] = o;
}

// ---------------- Phase 4: fuse W = [[Wl1,Wr1],[Wl2,Wr2]] -> bf16 [1024][1024] ----------------
__global__ void wconv_kernel(const float* __restrict__ Wl1, const float* __restrict__ Wr1,
                             const float* __restrict__ Wl2, const float* __restrict__ Wr2,
                             unsigned short* __restrict__ Wb) {
    int i = blockIdx.x * blockDim.x + threadIdx.x;
    if (i < NDIM * KDIM) {
        int n = i >> 10, k = i & 1023;
        const float* src;
        if (n < 512) src = (k < 512) ? Wl1 : Wr1;
        else         src = (k < 512) ? Wl2 : Wr2;
        int nn = n & 511, kk = k & 511;
        Wb[i] = f2bf(src[nn * 512 + kk]);
    }
}

// ---------------- Phase 5: GEMM C = H @ W^T with fused epilogue ----------------
// H row = [aggb row | xb row] (both stride 512), W as Wb [N=1024][K=1024] row-major (B^T form)
#define BM 128
#define BN 128
#define BK 32

__device__ __forceinline__ void async_copy16(const void* g, void* lds) {
    __builtin_amdgcn_global_load_lds((const __attribute__((address_space(1))) void*)g,
                                     (__attribute__((address_space(3))) void*)lds, 16, 0, 0);
}

__global__ __launch_bounds__(256, 2) void gemm_kernel(
    const unsigned short* __restrict__ aggb,   // [M,512] bf16
    const unsigned short* __restrict__ xb,     // [M,512] bf16
    const unsigned short* __restrict__ Wb,     // [1024,1024] bf16
    const float* __restrict__ bl1, const float* __restrict__ bl2,
    float* __restrict__ out) {
    constexpr int M = N_NODES;
    __shared__ unsigned short sA[BM * BK];
    __shared__ unsigned short sB[BN * BK];

    int m0 = blockIdx.x * BM;
    int n0 = blockIdx.y * BN;
    int tid = threadIdx.x;
    int lane = tid & 63;
    int w = tid >> 6;
    int wm = (w >> 1) * 64, wn = (w & 1) * 64;

    f32x4 acc[4][4] = {};

    // staging geometry: chunk = iss*256 + w*64 + lane; 16B chunk; row = chunk>>2, kcol = (chunk&3)*8
    int cbase = w * 64 + lane;
    int arow0 = cbase >> 2;        // 0..63
    int kc = (cbase & 3) * 8;

    int fr = lane & 15, q = lane >> 4;

    for (int k0 = 0; k0 < KDIM; k0 += BK) {
        const unsigned short* Asrc;
        int ak;
        if (k0 < 512) { Asrc = aggb; ak = k0; } else { Asrc = xb; ak = k0 - 512; }
        #pragma unroll
        for (int iss = 0; iss < 2; ++iss) {
            int row = arow0 + iss * 64;
            int gr = m0 + row; if (gr >= M) gr = M - 1;
            const unsigned short* g = Asrc + (size_t)gr * 512 + ak + kc;
            // LDS dest: wave-uniform base; HW adds lane*16B
            async_copy16(g, sA + (size_t)(iss * 256 + w * 64) * 8);
        }
        #pragma unroll
        for (int iss = 0; iss < 2; ++iss) {
            int row = arow0 + iss * 64;
            const unsigned short* g = Wb + (size_t)(n0 + row) * KDIM + k0 + kc;
            async_copy16(g, sB + (size_t)(iss * 256 + w * 64) * 8);
        }
        __syncthreads();

        bf16x8 af[4], bfg[4];
        #pragma unroll
        for (int i = 0; i < 4; ++i)
            af[i] = *(const bf16x8*)(sA + (wm + i * 16 + fr) * BK + q * 8);
        #pragma unroll
        for (int j = 0; j < 4; ++j)
            bfg[j] = *(const bf16x8*)(sB + (wn + j * 16 + fr) * BK + q * 8);
        #pragma unroll
        for (int i = 0; i < 4; ++i)
            #pragma unroll
            for (int j = 0; j < 4; ++j)
                acc[i][j] = __builtin_amdgcn_mfma_f32_16x16x32_bf16(af[i], bfg[j], acc[i][j], 0, 0, 0);
        __syncthreads();
    }

    // epilogue: C/D layout col = lane&15, row = (lane>>4)*4 + reg
    bool is_scale = (n0 >= 512);                 // BN=128 divides 512, so uniform per block
    const float* bias = is_scale ? bl2 : bl1;
    float* obase = out + (is_scale ? (size_t)N_NODES * OUT_DIM : 0);
    int ncol0 = is_scale ? (n0 - 512) : n0;
    int rq = lane >> 4;
    #pragma unroll
    for (int i = 0; i < 4; ++i) {
        #pragma unroll
        for (int j = 0; j < 4; ++j) {
            int colg = ncol0 + wn + j * 16 + fr;
            float b = bias[colg];
            #pragma unroll
            for (int r = 0; r < 4; ++r) {
                int rowg = m0 + wm + i * 16 + rq * 4 + r;
                if (rowg < M) {
                    float v = acc[i][j][r] + b;
                    float res;
                    if (is_scale) {
                        float sp = (v > 0.f) ? (v + log1pf(__expf(-v))) : log1pf(__expf(v));
                        res = fminf(sp + 0.001f, 100.f);
                    } else {
                        res = fminf(fmaxf(v, -100.f), 100.f);
                    }
                    obase[(size_t)rowg * OUT_DIM + colg] = res;
                }
            }
        }
    }
}

extern "C" void kernel_launch(void* const* d_in, const int* in_sizes, int n_in,
                              void* d_out, int out_size, void* d_ws, size_t ws_size,
                              hipStream_t stream) {
    const float* x       = (const float*)d_in[0];
    const int* ei        = (const int*)d_in[1];   // int inputs delivered as int32
    const float* Wl1     = (const float*)d_in[2];
    const float* bl1     = (const float*)d_in[3];
    const float* Wr1     = (const float*)d_in[4];
    const float* Wl2     = (const float*)d_in[5];
    const float* bl2     = (const float*)d_in[6];
    const float* Wr2     = (const float*)d_in[7];
    float* out = (float*)d_out;

    char* ws = (char*)d_ws;
    size_t off = 0;
    auto alloc = [&](size_t bytes) -> void* {
        void* p = ws + off;
        off = (off + bytes + 255) & ~(size_t)255;
        return p;
    };
    unsigned short* xb    = (unsigned short*)alloc((size_t)N_NODES * IN_DIM * 2);  // 51.2 MB
    unsigned short* aggb  = (unsigned short*)alloc((size_t)N_NODES * IN_DIM * 2);  // 51.2 MB
    unsigned short* Wb    = (unsigned short*)alloc((size_t)NDIM * KDIM * 2);       // 2 MB
    int* counts           = (int*)alloc((size_t)(N_NODES + 1) * 4);
    int* offs             = (int*)alloc((size_t)(N_NODES + 1) * 4);
    int* cursor           = (int*)alloc((size_t)N_NODES * 4);
    int* bucket           = (int*)alloc((size_t)N_EDGES * 4);                      // 3.2 MB

    hipMemsetAsync(counts, 0, (size_t)(N_NODES + 1) * 4, stream);

    xconv_kernel<<<(N_NODES * IN_DIM / 4 + 255) / 256, 256, 0, stream>>>(x, xb);
    count_kernel<<<(N_EDGES + 255) / 256, 256, 0, stream>>>(ei, counts);
    scan_kernel<<<1, 1024, 0, stream>>>(counts, offs, cursor, N_NODES);
    fill_kernel<<<(N_EDGES + 255) / 256, 256, 0, stream>>>(ei, cursor, bucket);
    aggregate_kernel<<<N_NODES, 256, 0, stream>>>(xb, offs, bucket, aggb);
    wconv_kernel<<<(NDIM * KDIM + 255) / 256, 256, 0, stream>>>(Wl1, Wr1, Wl2, Wr2, Wb);

    dim3 g((N_NODES + BM - 1) / BM, NDIM / BN);
    gemm_kernel<<<g, 256, 0, stream>>>(aggb, xb, Wb, bl1, bl2, out);
}